// Round 1
// 1835.994 us; speedup vs baseline: 1.5653x; 1.5653x over previous
//
#include <hip/hip_runtime.h>
#include <math.h>

#define RR 3
#define NN 300000
#define HH 256
#define GG 2048

typedef __attribute__((ext_vector_type(8))) short bf16x8;
typedef __attribute__((ext_vector_type(4))) float f32x4;

// ---------------- helpers ----------------
__device__ __forceinline__ ushort f2bf(float f) {
  union { float f; unsigned u; } v; v.f = f;
  unsigned u = v.u;
  u += 0x7fffu + ((u >> 16) & 1u);     // RNE
  return (ushort)(u >> 16);
}
__device__ __forceinline__ float bf2f(ushort h) {
  union { float f; unsigned u; } v; v.u = ((unsigned)h) << 16;
  return v.f;
}
__device__ __forceinline__ float tanh_fast(float x) {
  // tanh(x) = 1 - 2/(exp(2x)+1); saturates correctly for |x| large
  const float e = __expf(2.f * x);
  return 1.f - 2.f / (e + 1.f);
}

__device__ __forceinline__ float block_reduce_sum(float v, float* rbuf) {
  const int tid = threadIdx.x;
  rbuf[tid] = v;
  __syncthreads();
  #pragma unroll
  for (int off = 128; off > 0; off >>= 1) {
    if (tid < off) rbuf[tid] = rbuf[tid] + rbuf[tid + off];
    __syncthreads();
  }
  const float r = rbuf[0];
  __syncthreads();
  return r;
}

__device__ __forceinline__ float block_reduce_max(float v, float* rbuf) {
  const int tid = threadIdx.x;
  rbuf[tid] = v;
  __syncthreads();
  #pragma unroll
  for (int off = 128; off > 0; off >>= 1) {
    if (tid < off) rbuf[tid] = fmaxf(rbuf[tid], rbuf[tid + off]);
    __syncthreads();
  }
  const float r = rbuf[0];
  __syncthreads();
  return r;
}

// ---------------- graph boundary kernel ----------------
__global__ void bounds_kernel(const int* __restrict__ batch, int* __restrict__ starts) {
  const int t = blockIdx.x * blockDim.x + threadIdx.x;
  if (t >= RR * (GG + 1)) return;
  const int r = t / (GG + 1);
  const int g = t - r * (GG + 1);
  const int* __restrict__ br = batch + (size_t)r * NN;
  int lo = 0, hi = NN;
  while (lo < hi) {
    const int mid = (lo + hi) >> 1;
    if (br[mid] < g) lo = mid + 1; else hi = mid;
  }
  starts[t] = lo;
}

// ---------------- W split/transpose prep ----------------
// Wt_hi/Wt_lo[r][j][k] = bf16 hi/lo split of W1[r][k][j]  (B^T layout for MFMA B-frags)
__global__ __launch_bounds__(256) void wsplit_kernel(
    const float* __restrict__ W1, ushort* __restrict__ Wt_hi, ushort* __restrict__ Wt_lo)
{
  const int t = blockIdx.x * 256 + threadIdx.x;
  if (t >= RR * HH * HH) return;
  const int r = t / (HH * HH);
  const int rem = t - r * (HH * HH);
  const int k = rem >> 8;
  const int j = rem & 255;
  const float w = W1[t];
  const ushort hi = f2bf(w);
  const ushort lo = f2bf(w - bf2f(hi));
  const size_t o = (size_t)r * HH * HH + (size_t)j * HH + k;
  Wt_hi[o] = hi;
  Wt_lo[o] = lo;
}

// ---------------- score kernel: s = tanh(h@W1+b1)@w2 + b2 via split-bf16 MFMA ----------------
// block = 4 waves, 128 nodes x 256 j. Wave w: nodes [32w,32w+32), all 256 j (2 phases of 128).
// Per wave per 32-k step: Tm=2 x Tj=8 16x16 tiles, 3 MFMAs each (hh, h*lo, lo*h).
// LDS: A/B tiles [128][64] bf16 hi+lo = 64KB, XOR-swizzled (byte ^= (row&7)<<4) for
// bank-balanced ds_read_b128 across 128B-stride rows.
constexpr int BM = 128;
constexpr int BK = 64;

__global__ __launch_bounds__(256, 2) void score_mfma_kernel(
    const float* __restrict__ h, const ushort* __restrict__ Wt_hi,
    const ushort* __restrict__ Wt_lo, const float* __restrict__ b1,
    const float* __restrict__ w2, const float* __restrict__ b2,
    float* __restrict__ s_out)
{
  const int r = blockIdx.y;
  const int n0 = blockIdx.x * BM;
  const int tid = threadIdx.x;
  const int lane = tid & 63;
  const int wid = tid >> 6;

  __shared__ ushort A_hi[BM * BK];
  __shared__ ushort A_lo[BM * BK];
  __shared__ ushort B_hi[128 * BK];
  __shared__ ushort B_lo[128 * BK];

  const float* __restrict__ hr = h + (size_t)r * NN * HH;
  const ushort* __restrict__ WhiR = Wt_hi + (size_t)r * HH * HH;
  const ushort* __restrict__ WloR = Wt_lo + (size_t)r * HH * HH;

  float p[2][4];
  #pragma unroll
  for (int m = 0; m < 2; ++m)
    #pragma unroll
    for (int q = 0; q < 4; ++q) p[m][q] = 0.f;

  for (int jp = 0; jp < 2; ++jp) {
    f32x4 acc[2][8];
    #pragma unroll
    for (int m = 0; m < 2; ++m)
      #pragma unroll
      for (int jt = 0; jt < 8; ++jt)
        acc[m][jt] = (f32x4){0.f, 0.f, 0.f, 0.f};

    for (int kb = 0; kb < 4; ++kb) {
      __syncthreads();   // previous tile's reads done before overwrite
      // ---- stage A: 128 nodes x 64 k fp32 -> bf16 hi/lo, swizzled ----
      #pragma unroll
      for (int it = 0; it < 8; ++it) {
        const int id = tid + 256 * it;       // 0..2047
        const int row = id >> 4;             // 0..127
        const int c4 = id & 15;              // float4 col: k-local = c4*4
        int gn = n0 + row; if (gn > NN - 1) gn = NN - 1;
        const float4 v = *(const float4*)(hr + (size_t)gn * HH + kb * 64 + c4 * 4);
        const ushort h0 = f2bf(v.x), h1 = f2bf(v.y), h2 = f2bf(v.z), h3 = f2bf(v.w);
        const ushort l0 = f2bf(v.x - bf2f(h0)), l1 = f2bf(v.y - bf2f(h1));
        const ushort l2 = f2bf(v.z - bf2f(h2)), l3 = f2bf(v.w - bf2f(h3));
        const int boff = row * 128 + ((c4 * 8) ^ ((row & 7) << 4));
        *(uint2*)((char*)A_hi + boff) =
            make_uint2((uint)h0 | ((uint)h1 << 16), (uint)h2 | ((uint)h3 << 16));
        *(uint2*)((char*)A_lo + boff) =
            make_uint2((uint)l0 | ((uint)l1 << 16), (uint)l2 | ((uint)l3 << 16));
      }
      // ---- stage B: 128 j x 64 k bf16 hi/lo from Wt (L2-resident), swizzled ----
      #pragma unroll
      for (int it = 0; it < 4; ++it) {
        const int id = tid + 256 * it;       // 0..1023
        const int jrow = id >> 3;            // 0..127
        const int kc = (id & 7) * 8;         // k element offset (8 bf16 per 16B)
        const size_t so = (size_t)(jp * 128 + jrow) * HH + kb * 64 + kc;
        const int boff = jrow * 128 + ((kc * 2) ^ ((jrow & 7) << 4));
        *(uint4*)((char*)B_hi + boff) = *(const uint4*)(WhiR + so);
        *(uint4*)((char*)B_lo + boff) = *(const uint4*)(WloR + so);
      }
      __syncthreads();

      // ---- compute: 2 k-steps of 32 ----
      #pragma unroll
      for (int ks = 0; ks < 2; ++ks) {
        const int cb = ks * 64 + ((lane >> 4) << 4);
        bf16x8 ahi[2], alo[2];
        #pragma unroll
        for (int m = 0; m < 2; ++m) {
          const int row = (wid << 5) + (m << 4) + (lane & 15);
          const int off = row * 128 + (cb ^ ((row & 7) << 4));
          ahi[m] = *(const bf16x8*)((const char*)A_hi + off);
          alo[m] = *(const bf16x8*)((const char*)A_lo + off);
        }
        #pragma unroll
        for (int jt = 0; jt < 8; ++jt) {
          const int jr = (jt << 4) + (lane & 15);
          const int off = jr * 128 + (cb ^ ((jr & 7) << 4));
          const bf16x8 bhi = *(const bf16x8*)((const char*)B_hi + off);
          const bf16x8 blo = *(const bf16x8*)((const char*)B_lo + off);
          #pragma unroll
          for (int m = 0; m < 2; ++m) {
            acc[m][jt] = __builtin_amdgcn_mfma_f32_16x16x32_bf16(ahi[m], bhi, acc[m][jt], 0, 0, 0);
            acc[m][jt] = __builtin_amdgcn_mfma_f32_16x16x32_bf16(ahi[m], blo, acc[m][jt], 0, 0, 0);
            acc[m][jt] = __builtin_amdgcn_mfma_f32_16x16x32_bf16(alo[m], bhi, acc[m][jt], 0, 0, 0);
          }
        }
      }
    }

    // ---- epilogue for this j-phase: tanh, dot w2 into per-thread partials ----
    // C/D layout: col = lane&15 (j), row = (lane>>4)*4 + q (node)
    #pragma unroll
    for (int jt = 0; jt < 8; ++jt) {
      const int j = jp * 128 + (jt << 4) + (lane & 15);
      const float bb = b1[r * HH + j];
      const float ww = w2[r * HH + j];
      #pragma unroll
      for (int m = 0; m < 2; ++m)
        #pragma unroll
        for (int q = 0; q < 4; ++q)
          p[m][q] = fmaf(tanh_fast(acc[m][jt][q] + bb), ww, p[m][q]);
    }
  }

  // ---- reduce the 16 j-columns per quarter-wave, store s ----
  const float bias2 = b2[r];
  #pragma unroll
  for (int m = 0; m < 2; ++m)
    #pragma unroll
    for (int q = 0; q < 4; ++q) {
      float v = p[m][q];
      v += __shfl_xor(v, 1);
      v += __shfl_xor(v, 2);
      v += __shfl_xor(v, 4);
      v += __shfl_xor(v, 8);
      if ((lane & 15) == 0) {
        const int node = n0 + (wid << 5) + (m << 4) + ((lane >> 4) << 2) + q;
        if (node < NN) s_out[(size_t)r * NN + node] = v + bias2;
      }
    }
}

// ---------------- pooling + fused rank_proj ----------------
constexpr int GPB = 4;

__global__ __launch_bounds__(256) void pool_kernel(
    const float* __restrict__ h, const int* __restrict__ starts,
    const float* __restrict__ s, const float* __restrict__ Wp,
    const float* __restrict__ bp, float* __restrict__ state)
{
  const int r = blockIdx.y;
  const int tid = threadIdx.x;
  __shared__ float agg[GPB][4 * HH];
  __shared__ float rbuf[256];
  const float* __restrict__ hr = h + (size_t)r * NN * HH;
  const float* __restrict__ sr = s + (size_t)r * NN;
  const int* __restrict__ str = starts + r * (GG + 1);

  for (int gg = 0; gg < GPB; ++gg) {
    const int g = blockIdx.x * GPB + gg;
    const int a = str[g];
    const int bnd = str[g + 1];
    const int cnt = bnd - a;

    float lm = -3.402823466e38f;
    for (int i = a + tid; i < bnd; i += 256) lm = fmaxf(lm, sr[i]);
    const float m = block_reduce_max(lm, rbuf);

    float le = 0.f;
    for (int i = a + tid; i < bnd; i += 256) le += expf(sr[i] - m);
    const float denom = block_reduce_sum(le, rbuf);

    float att = 0.f, smv = 0.f, mxv = -3.402823466e38f;
    #pragma unroll 2
    for (int n = a; n < bnd; ++n) {
      const float e = expf(sr[n] - m);
      const float hv = hr[(size_t)n * HH + tid];
      att += e * hv;
      smv += hv;
      mxv = fmaxf(mxv, hv);
    }
    const float meanv = smv / fmaxf((float)cnt, 1.f);
    if (cnt == 0) { mxv = 0.f; att = 0.f; } else { att /= denom; }
    agg[gg][tid]          = smv;
    agg[gg][HH + tid]     = meanv;
    agg[gg][2 * HH + tid] = mxv;
    agg[gg][3 * HH + tid] = att;
  }
  __syncthreads();

  const float* __restrict__ Wpr = Wp + (size_t)r * 4 * HH * HH;
  float o[GPB];
  #pragma unroll
  for (int gg = 0; gg < GPB; ++gg) o[gg] = bp[r * HH + tid];
  for (int i = 0; i < 4 * HH; ++i) {
    const float w = Wpr[(size_t)i * HH + tid];
    #pragma unroll
    for (int gg = 0; gg < GPB; ++gg) o[gg] = fmaf(agg[gg][i], w, o[gg]);
  }
  #pragma unroll
  for (int gg = 0; gg < GPB; ++gg) {
    const int g = blockIdx.x * GPB + gg;
    state[(size_t)g * (RR * HH) + r * HH + tid] = o[gg];
  }
}

// ---------------- final MLP: LN -> SiLU -> Wf1 -> SiLU -> Wf2 ----------------
__global__ __launch_bounds__(256) void final_kernel(
    const float* __restrict__ state, const float* __restrict__ ln_g,
    const float* __restrict__ ln_b, const float* __restrict__ Wf1,
    const float* __restrict__ bf1, const float* __restrict__ Wf2,
    const float* __restrict__ bf2, float* __restrict__ out)
{
  const int g = blockIdx.x;
  const int tid = threadIdx.x;
  __shared__ float x_lds[RR * HH];
  __shared__ float rbuf[256];
  const float* __restrict__ st = state + (size_t)g * (RR * HH);

  float v[3];
  float lsum = 0.f, lsq = 0.f;
  #pragma unroll
  for (int p = 0; p < 3; ++p) {
    v[p] = st[tid + 256 * p];
    lsum += v[p];
    lsq += v[p] * v[p];
  }
  const float S = block_reduce_sum(lsum, rbuf);
  const float Q = block_reduce_sum(lsq, rbuf);
  const float mu = S * (1.f / 768.f);
  const float var = Q * (1.f / 768.f) - mu * mu;
  const float rstd = rsqrtf(var + 1e-5f);
  #pragma unroll
  for (int p = 0; p < 3; ++p) {
    const int idx = tid + 256 * p;
    float x = (v[p] - mu) * rstd * ln_g[idx] + ln_b[idx];
    x = x / (1.f + expf(-x));
    x_lds[idx] = x;
  }
  __syncthreads();

  float acc = bf1[tid];
  #pragma unroll 4
  for (int i = 0; i < RR * HH; ++i)
    acc = fmaf(x_lds[i], Wf1[(size_t)i * HH + tid], acc);
  const float y = acc / (1.f + expf(-acc));
  const float T = block_reduce_sum(y * Wf2[tid], rbuf);
  if (tid == 0) out[g] = T + bf2[0];
}

// ---------------- launch ----------------
extern "C" void kernel_launch(void* const* d_in, const int* in_sizes, int n_in,
                              void* d_out, int out_size, void* d_ws, size_t ws_size,
                              hipStream_t stream)
{
  const float* h    = (const float*)d_in[0];
  const int*   batch= (const int*)  d_in[1];
  const float* W1   = (const float*)d_in[2];
  const float* b1   = (const float*)d_in[3];
  const float* w2   = (const float*)d_in[4];
  const float* b2   = (const float*)d_in[5];
  const float* Wp   = (const float*)d_in[6];
  const float* bp   = (const float*)d_in[7];
  const float* ln_g = (const float*)d_in[8];
  const float* ln_b = (const float*)d_in[9];
  const float* Wf1  = (const float*)d_in[10];
  const float* bf1  = (const float*)d_in[11];
  const float* Wf2  = (const float*)d_in[12];
  const float* bf2  = (const float*)d_in[13];
  float* out = (float*)d_out;

  // workspace layout:
  //   s:      R*N floats   = 3,600,000 B at 0
  //   starts: R*(G+1) ints   at 3,600,000 (32KB reserved)
  //   state:  G*R*H floats = 6,291,456 B at 3,632,768
  //   Wt_hi:  R*H*H bf16   =   393,216 B at 9,924,224
  //   Wt_lo:  R*H*H bf16   =   393,216 B at 10,317,440   (total 10,710,656)
  char* ws = (char*)d_ws;
  float*  s_buf  = (float*)ws;
  int*    starts = (int*)(ws + 3600000);
  float*  state  = (float*)(ws + 3632768);
  ushort* Wt_hi  = (ushort*)(ws + 9924224);
  ushort* Wt_lo  = (ushort*)(ws + 10317440);

  bounds_kernel<<<(RR * (GG + 1) + 255) / 256, 256, 0, stream>>>(batch, starts);

  wsplit_kernel<<<(RR * HH * HH + 255) / 256, 256, 0, stream>>>(W1, Wt_hi, Wt_lo);

  dim3 gs((NN + BM - 1) / BM, RR);
  score_mfma_kernel<<<gs, 256, 0, stream>>>(h, Wt_hi, Wt_lo, b1, w2, b2, s_buf);

  dim3 gp(GG / GPB, RR);
  pool_kernel<<<gp, 256, 0, stream>>>(h, starts, s_buf, Wp, bp, state);

  final_kernel<<<GG, 256, 0, stream>>>(state, ln_g, ln_b, Wf1, bf1, Wf2, bf2, out);

  (void)in_sizes; (void)n_in; (void)out_size; (void)ws_size;
}